// Round 1
// baseline (284.514 us; speedup 1.0000x reference)
//
#include <hip/hip_runtime.h>
#include <math.h>

#define NB 16
#define S1 128
#define S2 192
#define HH 256   // half hidden
#define PP 4
#define FULLH 512
#define EPSV 1e-8f

__device__ __forceinline__ float dot4(const float4& a, const float4& b) {
    return a.x * b.x + a.y * b.y + a.z * b.z + a.w * b.w;
}

template<int N>
__device__ __forceinline__ void wave_reduce_sum_n(float* v) {
#pragma unroll
    for (int m = 1; m < 64; m <<= 1) {
#pragma unroll
        for (int i = 0; i < N; i++) v[i] += __shfl_xor(v[i], m, 64);
    }
}

// One wave per (d, b, j): compute ||q2_d[b,j]|| and ||q2_d[b,j] * W[2+d][p]|| for p=0..3
__global__ __launch_bounds__(256) void norms_kernel(const float* __restrict__ q2,
                                                    const float* __restrict__ W,
                                                    float* __restrict__ n2out,
                                                    float* __restrict__ n2wout) {
    int gwid = (int)((blockIdx.x * blockDim.x + threadIdx.x) >> 6);
    int lane = threadIdx.x & 63;
    if (gwid >= 2 * NB * S2) return;
    int d = gwid / (NB * S2);
    int rem = gwid - d * (NB * S2);
    int b = rem / S2;
    int j = rem - b * S2;

    const float* q2row = q2 + ((size_t)b * S2 + j) * FULLH + d * HH;
    int h0 = lane * 4;
    float4 v = *reinterpret_cast<const float4*>(q2row + h0);
    const float* wmax = W + (size_t)(2 + d) * PP * HH;

    float s[5];
    s[0] = dot4(v, v);
#pragma unroll
    for (int p = 0; p < PP; p++) {
        float4 wv = *reinterpret_cast<const float4*>(wmax + p * HH + h0);
        float4 t;
        t.x = v.x * wv.x; t.y = v.y * wv.y; t.z = v.z * wv.z; t.w = v.w * wv.w;
        s[1 + p] = dot4(t, t);
    }
    wave_reduce_sum_n<5>(s);
    if (lane == 0) {
        n2out[gwid] = sqrtf(s[0]);
#pragma unroll
        for (int p = 0; p < PP; p++) n2wout[(size_t)gwid * PP + p] = sqrtf(s[1 + p]);
    }
}

// One block (256 threads = 4 waves) per (b, i, d)
__global__ __launch_bounds__(256) void matching_kernel(const float* __restrict__ q1,
                                                       const float* __restrict__ q2,
                                                       const float* __restrict__ W,
                                                       const float* __restrict__ n2s_g,
                                                       const float* __restrict__ n2ws_g,
                                                       float* __restrict__ out) {
    __shared__ float lds_n2[S2];
    __shared__ float lds_n2w[S2 * PP];
    __shared__ float meanP[4][HH];
    __shared__ float maxattP[4][HH];
    __shared__ float sattP[4];
    __shared__ float maxcosP[4][PP];
    __shared__ float meanF[HH];
    __shared__ float maxattF[HH];

    int bid = blockIdx.x;
    int b = bid >> 8;
    int r = bid & 255;
    int i = r >> 1;
    int d = r & 1;
    int tid = threadIdx.x;
    int w = tid >> 6;
    int lane = tid & 63;
    int h0 = lane * 4;

    const float* q1row = q1 + ((size_t)(b * S1 + i)) * FULLH + d * HH;
    const float* q2base = q2 + (size_t)b * S2 * FULLH + d * HH;  // row stride FULLH

    // stage per-(b,j) q2 norms into LDS
    int nbase = d * (NB * S2) + b * S2;
    for (int t = tid; t < S2; t += 256) lds_n2[t] = n2s_g[nbase + t];
    for (int t = tid; t < S2 * PP; t += 256) lds_n2w[t] = n2ws_g[(size_t)nbase * PP + t];

    float4 q1v = *reinterpret_cast<const float4*>(q1row + h0);

    const float* wmax = W + (size_t)(2 + d) * PP * HH;
    float4 q1w2[PP];
    float pre[5];
    pre[0] = dot4(q1v, q1v);
#pragma unroll
    for (int p = 0; p < PP; p++) {
        float4 wv = *reinterpret_cast<const float4*>(wmax + p * HH + h0);
        float4 t;
        t.x = q1v.x * wv.x * wv.x;
        t.y = q1v.y * wv.y * wv.y;
        t.z = q1v.z * wv.z * wv.z;
        t.w = q1v.w * wv.w * wv.w;
        q1w2[p] = t;
        pre[1 + p] = dot4(q1v, t);  // sum q1^2 * w^2
    }
    wave_reduce_sum_n<5>(pre);
    float n1 = sqrtf(pre[0]);                  // unclamped (attention uses product clamp)
    float n1w0 = fmaxf(sqrtf(pre[1]), EPSV);
    float n1w1 = fmaxf(sqrtf(pre[2]), EPSV);
    float n1w2 = fmaxf(sqrtf(pre[3]), EPSV);
    float n1w3 = fmaxf(sqrtf(pre[4]), EPSV);

    __syncthreads();  // LDS norm staging complete

    float satt = 0.0f;
    float4 macc = make_float4(0.f, 0.f, 0.f, 0.f);
    float4 mx = make_float4(-INFINITY, -INFINITY, -INFINITY, -INFINITY);
    float mc0 = -INFINITY, mc1 = -INFINITY, mc2 = -INFINITY, mc3 = -INFINITY;

    for (int j = w; j < S2; j += 4) {
        float4 v = *reinterpret_cast<const float4*>(q2base + (size_t)j * FULLH + h0);
        float s[5];
        s[0] = dot4(q1v, v);
        s[1] = dot4(q1w2[0], v);
        s[2] = dot4(q1w2[1], v);
        s[3] = dot4(q1w2[2], v);
        s[4] = dot4(q1w2[3], v);
        wave_reduce_sum_n<5>(s);

        float den = n1 * lds_n2[j];
        float att = s[0] / (den > EPSV ? den : EPSV);
        satt += att;
        macc.x = fmaf(att, v.x, macc.x);
        macc.y = fmaf(att, v.y, macc.y);
        macc.z = fmaf(att, v.z, macc.z);
        macc.w = fmaf(att, v.w, macc.w);
        mx.x = fmaxf(mx.x, att * v.x);
        mx.y = fmaxf(mx.y, att * v.y);
        mx.z = fmaxf(mx.z, att * v.z);
        mx.w = fmaxf(mx.w, att * v.w);

        mc0 = fmaxf(mc0, s[1] / (n1w0 * fmaxf(lds_n2w[j * PP + 0], EPSV)));
        mc1 = fmaxf(mc1, s[2] / (n1w1 * fmaxf(lds_n2w[j * PP + 1], EPSV)));
        mc2 = fmaxf(mc2, s[3] / (n1w2 * fmaxf(lds_n2w[j * PP + 2], EPSV)));
        mc3 = fmaxf(mc3, s[4] / (n1w3 * fmaxf(lds_n2w[j * PP + 3], EPSV)));
    }

    // publish per-wave partials
    *reinterpret_cast<float4*>(&meanP[w][h0]) = macc;
    *reinterpret_cast<float4*>(&maxattP[w][h0]) = mx;
    if (lane == 0) {
        sattP[w] = satt;
        maxcosP[w][0] = mc0;
        maxcosP[w][1] = mc1;
        maxcosP[w][2] = mc2;
        maxcosP[w][3] = mc3;
    }
    __syncthreads();

    size_t obase = ((size_t)(b * S1 + i)) * 32;

    // cross-wave combine: thread t handles h = t
    {
        float msum = meanP[0][tid] + meanP[1][tid] + meanP[2][tid] + meanP[3][tid];
        float sat = sattP[0] + sattP[1] + sattP[2] + sattP[3];
        float denom = (sat > EPSV) ? sat : EPSV;
        meanF[tid] = msum / denom;
        maxattF[tid] = fmaxf(fmaxf(maxattP[0][tid], maxattP[1][tid]),
                             fmaxf(maxattP[2][tid], maxattP[3][tid]));
        if (tid < PP) {
            float m = fmaxf(fmaxf(maxcosP[0][tid], maxcosP[1][tid]),
                            fmaxf(maxcosP[2][tid], maxcosP[3][tid]));
            out[obase + 8 + 4 * d + tid] = m;  // max-pool matching
        }
    }
    __syncthreads();

    // final matchings: wave w == p
    {
        int p = w;
        const float* refrow = q2base + (d == 0 ? (size_t)(S2 - 1) * FULLH : (size_t)0);
        float4 rv = *reinterpret_cast<const float4*>(refrow + h0);
        float4 mv = *reinterpret_cast<const float4*>(&meanF[h0]);
        float4 xv = *reinterpret_cast<const float4*>(&maxattF[h0]);
        float4 wf = *reinterpret_cast<const float4*>(W + ((size_t)d * PP + p) * HH + h0);
        float4 wa = *reinterpret_cast<const float4*>(W + ((size_t)(4 + d) * PP + p) * HH + h0);
        float4 wm = *reinterpret_cast<const float4*>(W + ((size_t)(6 + d) * PP + p) * HH + h0);

        float s[9];
        // full matching: q1 vs ref with wf^2
        {
            float4 w2; w2.x = wf.x * wf.x; w2.y = wf.y * wf.y; w2.z = wf.z * wf.z; w2.w = wf.w * wf.w;
            s[0] = q1v.x * rv.x * w2.x + q1v.y * rv.y * w2.y + q1v.z * rv.z * w2.z + q1v.w * rv.w * w2.w;
            s[1] = q1v.x * q1v.x * w2.x + q1v.y * q1v.y * w2.y + q1v.z * q1v.z * w2.z + q1v.w * q1v.w * w2.w;
            s[2] = rv.x * rv.x * w2.x + rv.y * rv.y * w2.y + rv.z * rv.z * w2.z + rv.w * rv.w * w2.w;
        }
        // att-match: q1 vs mean with wa^2
        {
            float4 w2; w2.x = wa.x * wa.x; w2.y = wa.y * wa.y; w2.z = wa.z * wa.z; w2.w = wa.w * wa.w;
            s[3] = q1v.x * mv.x * w2.x + q1v.y * mv.y * w2.y + q1v.z * mv.z * w2.z + q1v.w * mv.w * w2.w;
            s[4] = q1v.x * q1v.x * w2.x + q1v.y * q1v.y * w2.y + q1v.z * q1v.z * w2.z + q1v.w * q1v.w * w2.w;
            s[5] = mv.x * mv.x * w2.x + mv.y * mv.y * w2.y + mv.z * mv.z * w2.z + mv.w * mv.w * w2.w;
        }
        // maxatt-match: q1 vs maxatt with wm^2
        {
            float4 w2; w2.x = wm.x * wm.x; w2.y = wm.y * wm.y; w2.z = wm.z * wm.z; w2.w = wm.w * wm.w;
            s[6] = q1v.x * xv.x * w2.x + q1v.y * xv.y * w2.y + q1v.z * xv.z * w2.z + q1v.w * xv.w * w2.w;
            s[7] = q1v.x * q1v.x * w2.x + q1v.y * q1v.y * w2.y + q1v.z * q1v.z * w2.z + q1v.w * q1v.w * w2.w;
            s[8] = xv.x * xv.x * w2.x + xv.y * xv.y * w2.y + xv.z * xv.z * w2.z + xv.w * xv.w * w2.w;
        }
        wave_reduce_sum_n<9>(s);
        if (lane == 0) {
            out[obase + 0 + 4 * d + p] =
                s[0] / (fmaxf(sqrtf(s[1]), EPSV) * fmaxf(sqrtf(s[2]), EPSV));
            out[obase + 16 + 4 * d + p] =
                s[3] / (fmaxf(sqrtf(s[4]), EPSV) * fmaxf(sqrtf(s[5]), EPSV));
            out[obase + 24 + 4 * d + p] =
                s[6] / (fmaxf(sqrtf(s[7]), EPSV) * fmaxf(sqrtf(s[8]), EPSV));
        }
    }
}

extern "C" void kernel_launch(void* const* d_in, const int* in_sizes, int n_in,
                              void* d_out, int out_size, void* d_ws, size_t ws_size,
                              hipStream_t stream) {
    const float* q1 = (const float*)d_in[0];
    const float* q2 = (const float*)d_in[1];
    const float* W = (const float*)d_in[2];
    float* out = (float*)d_out;
    float* ws = (float*)d_ws;

    float* n2s = ws;                       // 2*16*192 = 6144 floats
    float* n2ws = ws + 2 * NB * S2;        // 6144*4 = 24576 floats

    int nwaves = 2 * NB * S2;                         // 6144
    int nblocks_norm = (nwaves * 64 + 255) / 256;     // 1536
    norms_kernel<<<dim3(nblocks_norm), dim3(256), 0, stream>>>(q2, W, n2s, n2ws);

    matching_kernel<<<dim3(NB * S1 * 2), dim3(256), 0, stream>>>(q1, q2, W, n2s, n2ws, out);
}

// Round 2
// 142.141 us; speedup vs baseline: 2.0016x; 2.0016x over previous
//
#include <hip/hip_runtime.h>
#include <math.h>

#define NB 16
#define S1 128
#define S2 192
#define HH 256   // half hidden
#define PP 4
#define FULLH 512
#define EPSV 1e-8f

// ---- workspace layout (floats) ----
#define WS_N2    0                         // 2*NB*S2          = 6144
#define WS_N2W   (WS_N2 + 2*NB*S2)         // 2*NB*S2*4        = 24576
#define WS_N1    (WS_N2W + 2*NB*S2*4)      // 2*NB*S1          = 4096
#define WS_N1W   (WS_N1 + 2*NB*S1)         // 2*NB*S1*4        = 16384
#define WS_SATT  (WS_N1W + 2*NB*S1*4)      // 2*NB*S1          = 4096
#define WS_ATT   (WS_SATT + 2*NB*S1)       // 2*NB*S1*S2       = 786432
// total ~3.37 MB

__device__ __forceinline__ float dot4(const float4& a, const float4& b) {
    return a.x * b.x + a.y * b.y + a.z * b.z + a.w * b.w;
}

template<int N>
__device__ __forceinline__ void wave_reduce_sum_n(float* v) {
#pragma unroll
    for (int m = 1; m < 64; m <<= 1) {
#pragma unroll
        for (int i = 0; i < N; i++) v[i] += __shfl_xor(v[i], m, 64);
    }
}

// One wave per row: q2 rows (2*NB*S2) then q1 rows (2*NB*S1).
// Computes plain norm + 4 weighted (W[2+d]) norms, unclamped sqrt.
__global__ __launch_bounds__(256) void norms_kernel(const float* __restrict__ q1,
                                                    const float* __restrict__ q2,
                                                    const float* __restrict__ W,
                                                    float* __restrict__ ws) {
    const int NQ2 = 2 * NB * S2;   // 6144
    const int NQ1 = 2 * NB * S1;   // 4096
    int gwid = (int)((blockIdx.x * blockDim.x + threadIdx.x) >> 6);
    int lane = threadIdx.x & 63;
    if (gwid >= NQ2 + NQ1) return;

    const float* row;
    int d;
    float* nout;
    float* nwout;
    if (gwid < NQ2) {
        d = gwid / (NB * S2);
        int rem = gwid - d * (NB * S2);
        int b = rem / S2;
        int j = rem - b * S2;
        row = q2 + ((size_t)(b * S2 + j)) * FULLH + d * HH;
        nout = ws + WS_N2 + gwid;
        nwout = ws + WS_N2W + (size_t)gwid * PP;
    } else {
        int idx = gwid - NQ2;
        d = idx >> 11;             // NB*S1 = 2048 per d
        int b = (idx >> 7) & 15;
        int i = idx & 127;
        row = q1 + ((size_t)(b * S1 + i)) * FULLH + d * HH;
        nout = ws + WS_N1 + idx;
        nwout = ws + WS_N1W + (size_t)idx * PP;
    }

    int h0 = lane * 4;
    float4 v = *reinterpret_cast<const float4*>(row + h0);
    const float* wmax = W + (size_t)(2 + d) * PP * HH;

    float s[5];
    s[0] = dot4(v, v);
#pragma unroll
    for (int p = 0; p < PP; p++) {
        float4 wv = *reinterpret_cast<const float4*>(wmax + p * HH + h0);
        float4 t;
        t.x = v.x * wv.x; t.y = v.y * wv.y; t.z = v.z * wv.z; t.w = v.w * wv.w;
        s[1 + p] = dot4(t, t);
    }
    wave_reduce_sum_n<5>(s);
    if (lane == 0) {
        nout[0] = sqrtf(s[0]);
#pragma unroll
        for (int p = 0; p < PP; p++) nwout[p] = sqrtf(s[1 + p]);
    }
}

// Score kernel: block per (b, d, itile of 8). 256 threads = 8 ii x 32 jj,
// each thread owns i = itile*8+ii and j in {jj, jj+32, ..., jj+160} (6 js).
// acc[jk][v]: v=0 plain dot (-> att), v=1..4 weighted dots (-> maxpool cos).
__global__ __launch_bounds__(256) void s_kernel(const float* __restrict__ q1,
                                                const float* __restrict__ q2,
                                                const float* __restrict__ W,
                                                float* __restrict__ ws,
                                                float* __restrict__ out) {
    __shared__ float q1s5[5][8][HH];   // 40 KB: q1 and q1*w_p^2 rows

    int bid = blockIdx.x;
    int it = bid & 15;
    int b = (bid >> 4) & 15;
    int d = bid >> 8;
    int tid = threadIdx.x;
    int jj = tid & 31;
    int ii = tid >> 5;
    int i = it * 8 + ii;

    // stage the 5 A-variants (coalesced: thread -> (row ii, 8 cols))
    {
        int c0 = jj * 8;
        const float* q1row = q1 + ((size_t)(b * S1 + i)) * FULLH + d * HH;
        float4 a0 = *reinterpret_cast<const float4*>(q1row + c0);
        float4 a1 = *reinterpret_cast<const float4*>(q1row + c0 + 4);
        *reinterpret_cast<float4*>(&q1s5[0][ii][c0]) = a0;
        *reinterpret_cast<float4*>(&q1s5[0][ii][c0 + 4]) = a1;
#pragma unroll
        for (int v = 1; v < 5; v++) {
            const float* wrow = W + ((size_t)(2 + d) * PP + (v - 1)) * HH;
            float4 w0 = *reinterpret_cast<const float4*>(wrow + c0);
            float4 w1 = *reinterpret_cast<const float4*>(wrow + c0 + 4);
            float4 t0, t1;
            t0.x = a0.x * w0.x * w0.x; t0.y = a0.y * w0.y * w0.y;
            t0.z = a0.z * w0.z * w0.z; t0.w = a0.w * w0.w * w0.w;
            t1.x = a1.x * w1.x * w1.x; t1.y = a1.y * w1.y * w1.y;
            t1.z = a1.z * w1.z * w1.z; t1.w = a1.w * w1.w * w1.w;
            *reinterpret_cast<float4*>(&q1s5[v][ii][c0]) = t0;
            *reinterpret_cast<float4*>(&q1s5[v][ii][c0 + 4]) = t1;
        }
    }
    __syncthreads();

    int q1idx = d * (NB * S1) + b * S1 + i;
    float n1 = ws[WS_N1 + q1idx];
    float n1wp[4];
#pragma unroll
    for (int p = 0; p < 4; p++) n1wp[p] = fmaxf(ws[WS_N1W + (size_t)q1idx * 4 + p], EPSV);

    float acc[6][5];
#pragma unroll
    for (int jk = 0; jk < 6; jk++)
#pragma unroll
        for (int v = 0; v < 5; v++) acc[jk][v] = 0.f;

    const float* q2base = q2 + (size_t)b * S2 * FULLH + d * HH;
#pragma unroll 2
    for (int h4 = 0; h4 < 64; h4++) {
        float4 a[5];
#pragma unroll
        for (int v = 0; v < 5; v++)
            a[v] = *reinterpret_cast<const float4*>(&q1s5[v][ii][h4 * 4]);
#pragma unroll
        for (int jk = 0; jk < 6; jk++) {
            float4 qv = *reinterpret_cast<const float4*>(
                q2base + (size_t)(jj + 32 * jk) * FULLH + h4 * 4);
#pragma unroll
            for (int v = 0; v < 5; v++) acc[jk][v] += dot4(a[v], qv);
        }
    }

    int nbase = d * (NB * S2) + b * S2;
    float* attrow = ws + WS_ATT + ((size_t)(d * NB + b) * S1 + i) * S2;
    float satt = 0.f;
    float mc[4] = {-INFINITY, -INFINITY, -INFINITY, -INFINITY};
#pragma unroll
    for (int jk = 0; jk < 6; jk++) {
        int j = jj + 32 * jk;
        float n2 = ws[WS_N2 + nbase + j];
        float den = n1 * n2;
        float att = acc[jk][0] / (den > EPSV ? den : EPSV);
        attrow[j] = att;
        satt += att;
#pragma unroll
        for (int p = 0; p < 4; p++) {
            float n2wv = fmaxf(ws[WS_N2W + (size_t)(nbase + j) * 4 + p], EPSV);
            mc[p] = fmaxf(mc[p], acc[jk][1 + p] / (n1wp[p] * n2wv));
        }
    }

    // reduce over the 32 jj lanes (half-wave butterfly; xor<32 stays in group)
#pragma unroll
    for (int m = 1; m < 32; m <<= 1) {
        satt += __shfl_xor(satt, m, 64);
#pragma unroll
        for (int p = 0; p < 4; p++) mc[p] = fmaxf(mc[p], __shfl_xor(mc[p], m, 64));
    }
    if (jj == 0) {
        ws[WS_SATT + q1idx] = satt;
        size_t obase = ((size_t)(b * S1 + i)) * 32;
#pragma unroll
        for (int p = 0; p < 4; p++) out[obase + 8 + 4 * d + p] = mc[p];
    }
}

// Apply kernel: one wave per (b, i, d). Lane owns a float4 h-chunk.
// att row is wave-uniform (scalar loads). Computes mean/maxatt and the
// 12 remaining cosines (full / att-match / maxatt-match).
__global__ __launch_bounds__(64) void apply_kernel(const float* __restrict__ q1,
                                                   const float* __restrict__ q2,
                                                   const float* __restrict__ W,
                                                   const float* __restrict__ ws,
                                                   float* __restrict__ out) {
    int bid = blockIdx.x;
    int b = bid >> 8;
    int i = (bid >> 1) & 127;
    int d = bid & 1;
    int lane = threadIdx.x;
    int h0 = lane * 4;

    const float* q1row = q1 + ((size_t)(b * S1 + i)) * FULLH + d * HH;
    float4 q1v = *reinterpret_cast<const float4*>(q1row + h0);
    const float* q2base = q2 + (size_t)b * S2 * FULLH + d * HH;
    const float* attrow = ws + WS_ATT + ((size_t)(d * NB + b) * S1 + i) * S2;
    float satt = ws[WS_SATT + d * (NB * S1) + b * S1 + i];

    float4 macc = make_float4(0.f, 0.f, 0.f, 0.f);
    float4 mx = make_float4(-INFINITY, -INFINITY, -INFINITY, -INFINITY);
#pragma unroll 4
    for (int j = 0; j < S2; j++) {
        float att = attrow[j];
        float4 qv = *reinterpret_cast<const float4*>(q2base + (size_t)j * FULLH + h0);
        macc.x = fmaf(att, qv.x, macc.x);
        macc.y = fmaf(att, qv.y, macc.y);
        macc.z = fmaf(att, qv.z, macc.z);
        macc.w = fmaf(att, qv.w, macc.w);
        mx.x = fmaxf(mx.x, att * qv.x);
        mx.y = fmaxf(mx.y, att * qv.y);
        mx.z = fmaxf(mx.z, att * qv.z);
        mx.w = fmaxf(mx.w, att * qv.w);
    }
    float sden = satt > EPSV ? satt : EPSV;
    float4 mean;
    mean.x = macc.x / sden; mean.y = macc.y / sden;
    mean.z = macc.z / sden; mean.w = macc.w / sden;
    float4 rv = *reinterpret_cast<const float4*>(
        q2base + (d == 0 ? (size_t)(S2 - 1) * FULLH : (size_t)0) + h0);

    // 3 matchings x 4 p x {num, |q1w|^2, |xw|^2}
    float s[36];
#pragma unroll
    for (int m = 0; m < 3; m++) {
        float4 xv = (m == 0) ? rv : (m == 1) ? mean : mx;
        int wb = (m == 0) ? d : (m == 1) ? 4 + d : 6 + d;
#pragma unroll
        for (int p = 0; p < 4; p++) {
            float4 wv = *reinterpret_cast<const float4*>(W + ((size_t)wb * PP + p) * HH + h0);
            float4 w2;
            w2.x = wv.x * wv.x; w2.y = wv.y * wv.y;
            w2.z = wv.z * wv.z; w2.w = wv.w * wv.w;
            float4 t;  // q1 * w2
            t.x = q1v.x * w2.x; t.y = q1v.y * w2.y;
            t.z = q1v.z * w2.z; t.w = q1v.w * w2.w;
            float4 u;  // x * w2
            u.x = xv.x * w2.x; u.y = xv.y * w2.y;
            u.z = xv.z * w2.z; u.w = xv.w * w2.w;
            int base = (m * 4 + p) * 3;
            s[base + 0] = t.x * xv.x + t.y * xv.y + t.z * xv.z + t.w * xv.w;
            s[base + 1] = t.x * q1v.x + t.y * q1v.y + t.z * q1v.z + t.w * q1v.w;
            s[base + 2] = u.x * xv.x + u.y * xv.y + u.z * xv.z + u.w * xv.w;
        }
    }
    wave_reduce_sum_n<36>(s);
    if (lane == 0) {
        size_t obase = ((size_t)(b * S1 + i)) * 32;
        const int obm[3] = {0, 16, 24};
#pragma unroll
        for (int m = 0; m < 3; m++) {
#pragma unroll
            for (int p = 0; p < 4; p++) {
                int base = (m * 4 + p) * 3;
                out[obase + obm[m] + 4 * d + p] =
                    s[base] / (fmaxf(sqrtf(s[base + 1]), EPSV) *
                               fmaxf(sqrtf(s[base + 2]), EPSV));
            }
        }
    }
}

extern "C" void kernel_launch(void* const* d_in, const int* in_sizes, int n_in,
                              void* d_out, int out_size, void* d_ws, size_t ws_size,
                              hipStream_t stream) {
    const float* q1 = (const float*)d_in[0];
    const float* q2 = (const float*)d_in[1];
    const float* W = (const float*)d_in[2];
    float* out = (float*)d_out;
    float* ws = (float*)d_ws;

    // 1) norms: 10240 waves
    int nrows = 2 * NB * S2 + 2 * NB * S1;             // 10240
    int nblocks_norm = (nrows * 64 + 255) / 256;       // 2560
    norms_kernel<<<dim3(nblocks_norm), dim3(256), 0, stream>>>(q1, q2, W, ws);

    // 2) score matrices + att + satt + maxpool outputs
    s_kernel<<<dim3(2 * NB * (S1 / 8)), dim3(256), 0, stream>>>(q1, q2, W, ws, out);

    // 3) att-apply + remaining 24 outputs per (b,i)
    apply_kernel<<<dim3(NB * S1 * 2), dim3(64), 0, stream>>>(q1, q2, W, ws, out);
}

// Round 3
// 73.386 us; speedup vs baseline: 3.8769x; 1.9369x over previous
//
#include <hip/hip_runtime.h>
#include <math.h>
#include <stdint.h>

#define NB 16
#define S1 128
#define S2 192
#define HH 256   // half hidden
#define PP 4
#define FULLH 512
#define EPSV 1e-8f

typedef float f32x4 __attribute__((ext_vector_type(4)));
typedef short short8 __attribute__((ext_vector_type(8)));

// ---- workspace layout (float offsets) ----
#define WS_N2    0                 // 6144
#define WS_N2W   6144              // 24576
#define WS_N1    30720             // 4096
#define WS_N1W   34816             // 16384
#define WS_SATT  51200             // [4 jq][4096]
#define WS_MC    67584             // [4 jq][4096][4]
#define WS_ATT   133120            // [4096][192]
#define WS_Q2BF  919552            // uint16 area: [2*NB][12 jt][8 s][64 lane][8 bf16]
// total ~6.8 MB

__device__ __forceinline__ float dot4(const float4& a, const float4& b) {
    return a.x * b.x + a.y * b.y + a.z * b.z + a.w * b.w;
}

__device__ __forceinline__ uint16_t f2bf(float x) {
    union { float f; uint32_t u; } a;
    a.f = x;
    uint32_t r = a.u + 0x7FFF + ((a.u >> 16) & 1);  // RNE
    return (uint16_t)(r >> 16);
}

__device__ __forceinline__ uint32_t pk2(float a, float b) {
    return (uint32_t)f2bf(a) | ((uint32_t)f2bf(b) << 16);
}

template<int N>
__device__ __forceinline__ void wave_reduce_sum_n(float* v) {
#pragma unroll
    for (int m = 1; m < 64; m <<= 1) {
#pragma unroll
        for (int i = 0; i < N; i++) v[i] += __shfl_xor(v[i], m, 64);
    }
}

// One wave per row: q2 rows (2*NB*S2) then q1 rows (2*NB*S1).
// Computes plain norm + 4 weighted (W[2+d]) norms (unclamped sqrt).
// Additionally converts q2 rows to bf16 in MFMA frag-major layout.
__global__ __launch_bounds__(256) void norms_kernel(const float* __restrict__ q1,
                                                    const float* __restrict__ q2,
                                                    const float* __restrict__ W,
                                                    float* __restrict__ ws) {
    const int NQ2 = 2 * NB * S2;   // 6144
    const int NQ1 = 2 * NB * S1;   // 4096
    int gwid = (int)((blockIdx.x * blockDim.x + threadIdx.x) >> 6);
    int lane = threadIdx.x & 63;
    if (gwid >= NQ2 + NQ1) return;

    const float* row;
    int d;
    float* nout;
    float* nwout;
    bool isq2 = gwid < NQ2;
    int b_ = 0, j_ = 0;
    if (isq2) {
        d = gwid / (NB * S2);
        int rem = gwid - d * (NB * S2);
        b_ = rem / S2;
        j_ = rem - b_ * S2;
        row = q2 + ((size_t)(b_ * S2 + j_)) * FULLH + d * HH;
        nout = ws + WS_N2 + gwid;
        nwout = ws + WS_N2W + (size_t)gwid * PP;
    } else {
        int idx = gwid - NQ2;
        d = idx >> 11;
        int b = (idx >> 7) & 15;
        int i = idx & 127;
        row = q1 + ((size_t)(b * S1 + i)) * FULLH + d * HH;
        nout = ws + WS_N1 + idx;
        nwout = ws + WS_N1W + (size_t)idx * PP;
    }

    int h0 = lane * 4;
    float4 v = *reinterpret_cast<const float4*>(row + h0);
    const float* wmax = W + (size_t)(2 + d) * PP * HH;

    float s[5];
    s[0] = dot4(v, v);
#pragma unroll
    for (int p = 0; p < PP; p++) {
        float4 wv = *reinterpret_cast<const float4*>(wmax + p * HH + h0);
        float4 t;
        t.x = v.x * wv.x; t.y = v.y * wv.y; t.z = v.z * wv.z; t.w = v.w * wv.w;
        s[1 + p] = dot4(t, t);
    }
    wave_reduce_sum_n<5>(s);
    if (lane == 0) {
        nout[0] = sqrtf(s[0]);
#pragma unroll
        for (int p = 0; p < PP; p++) nwout[p] = sqrtf(s[1 + p]);
    }

    if (isq2) {
        // frag-major bf16: chunk (jt, s, l) holds q2[jt*16 + (l&15)][s*32 + (l>>4)*8 + e]
        uint16_t* q2bf = (uint16_t*)(ws + WS_Q2BF);
        size_t bdbase = (size_t)(d * NB + b_) * (S2 * HH);
        int jt = j_ >> 4, jcol = j_ & 15;
        int sg = lane >> 3;
        int khalf = (lane >> 1) & 3;
        int elo = (lane & 1) * 4;
        size_t off = bdbase + ((size_t)(jt * 8 + sg) * 64 + (khalf << 4) + jcol) * 8 + elo;
        uint2 pk;
        pk.x = pk2(v.x, v.y);
        pk.y = pk2(v.z, v.w);
        *reinterpret_cast<uint2*>(q2bf + off) = pk;
    }
}

// MFMA S-phase: 1 wave per block; block = (d, b, itile of 16 rows, jquarter of 48 cols).
// Computes S_v = A_v . q2^T for v=0 (plain -> att) and v=1..4 (q1*w_p^2 -> maxpool cos).
__global__ __launch_bounds__(64) void s_mfma_kernel(const float* __restrict__ q1,
                                                    const float* __restrict__ W,
                                                    float* __restrict__ ws) {
    __shared__ short lA[5 * 2 * 64 * 8];   // 10 KB, chunk (v, s_loc, lane)
    __shared__ short lB[6 * 64 * 8];       // 6 KB,  chunk (jt_i*2 + s_loc, lane)

    int bid = blockIdx.x;
    int jq = bid & 3;
    int itile = (bid >> 2) & 7;
    int b = (bid >> 5) & 15;
    int d = bid >> 9;
    int t = threadIdx.x;

    const uint16_t* q2bf = (const uint16_t*)(ws + WS_Q2BF) + (size_t)(d * NB + b) * (S2 * HH);

    f32x4 acc[5][3];
#pragma unroll
    for (int v = 0; v < 5; v++)
#pragma unroll
        for (int jt_i = 0; jt_i < 3; jt_i++) acc[v][jt_i] = (f32x4){0.f, 0.f, 0.f, 0.f};

    // A staging geometry (constant over kc): thread -> (row ar, 16 k starting at ak0)
    int ar = t >> 2;
    int ak0 = (t & 3) << 4;
    int a_sloc = ak0 >> 5;
    int a_kh = (ak0 >> 3) & 3;   // 0 or 2
    const float* q1row = q1 + ((size_t)(b * S1 + itile * 16 + ar)) * FULLH + d * HH;

    for (int kc = 0; kc < 4; kc++) {
        // stage B (linear copy of pre-converted frag-major bf16)
#pragma unroll
        for (int ci = 0; ci < 6; ci++) {
            int jt = jq * 3 + (ci >> 1);
            int sg = kc * 2 + (ci & 1);
            uint4 src = *reinterpret_cast<const uint4*>(
                q2bf + ((size_t)(jt * 8 + sg) * 64 + t) * 8);
            *reinterpret_cast<uint4*>(&lB[(ci * 64 + t) * 8]) = src;
        }
        // stage A: load q1 chunk, build 5 variants, convert to bf16 frag-major
        {
            int kg = kc * 64 + ak0;
            float4 x0 = *reinterpret_cast<const float4*>(q1row + kg);
            float4 x1 = *reinterpret_cast<const float4*>(q1row + kg + 4);
            float4 x2 = *reinterpret_cast<const float4*>(q1row + kg + 8);
            float4 x3 = *reinterpret_cast<const float4*>(q1row + kg + 12);
#pragma unroll
            for (int v = 0; v < 5; v++) {
                float4 y0 = x0, y1 = x1, y2 = x2, y3 = x3;
                if (v > 0) {
                    const float* wrow = W + ((size_t)((2 + d) * PP + (v - 1))) * HH + kg;
                    float4 w0 = *reinterpret_cast<const float4*>(wrow);
                    float4 w1 = *reinterpret_cast<const float4*>(wrow + 4);
                    float4 w2 = *reinterpret_cast<const float4*>(wrow + 8);
                    float4 w3 = *reinterpret_cast<const float4*>(wrow + 12);
                    y0.x *= w0.x * w0.x; y0.y *= w0.y * w0.y; y0.z *= w0.z * w0.z; y0.w *= w0.w * w0.w;
                    y1.x *= w1.x * w1.x; y1.y *= w1.y * w1.y; y1.z *= w1.z * w1.z; y1.w *= w1.w * w1.w;
                    y2.x *= w2.x * w2.x; y2.y *= w2.y * w2.y; y2.z *= w2.z * w2.z; y2.w *= w2.w * w2.w;
                    y3.x *= w3.x * w3.x; y3.y *= w3.y * w3.y; y3.z *= w3.z * w3.z; y3.w *= w3.w * w3.w;
                }
                uint4 c0, c1;
                c0.x = pk2(y0.x, y0.y); c0.y = pk2(y0.z, y0.w);
                c0.z = pk2(y1.x, y1.y); c0.w = pk2(y1.z, y1.w);
                c1.x = pk2(y2.x, y2.y); c1.y = pk2(y2.z, y2.w);
                c1.z = pk2(y3.x, y3.y); c1.w = pk2(y3.z, y3.w);
                int base = ((v * 2 + a_sloc) * 64 + (a_kh << 4) + ar) * 8;
                *reinterpret_cast<uint4*>(&lA[base]) = c0;
                *reinterpret_cast<uint4*>(&lA[base + 128]) = c1;   // khalf+1 -> +16 lanes
            }
        }
        __syncthreads();
#pragma unroll
        for (int sl = 0; sl < 2; sl++) {
            short8 a[5];
#pragma unroll
            for (int v = 0; v < 5; v++)
                a[v] = *reinterpret_cast<const short8*>(&lA[((v * 2 + sl) * 64 + t) * 8]);
#pragma unroll
            for (int jt_i = 0; jt_i < 3; jt_i++) {
                short8 bf = *reinterpret_cast<const short8*>(&lB[((jt_i * 2 + sl) * 64 + t) * 8]);
#pragma unroll
                for (int v = 0; v < 5; v++)
                    acc[v][jt_i] = __builtin_amdgcn_mfma_f32_16x16x32_bf16(a[v], bf, acc[v][jt_i], 0, 0, 0);
            }
        }
        __syncthreads();
    }

    // ---- epilogue ----
    // C layout: col = lane&15 (j within tile), row = (lane>>4)*4 + reg (i within tile)
    int lhi = t >> 4;
    int lcol = t & 15;
    int nbase = d * (NB * S2) + b * S2;
    int q1b = d * (NB * S1) + b * S1 + itile * 16 + lhi * 4;  // + rr

    float n1[4], n1wc[4][4];
#pragma unroll
    for (int rr = 0; rr < 4; rr++) {
        n1[rr] = ws[WS_N1 + q1b + rr];
#pragma unroll
        for (int p = 0; p < 4; p++)
            n1wc[rr][p] = fmaxf(ws[WS_N1W + (size_t)(q1b + rr) * 4 + p], EPSV);
    }

    float satt_acc[4] = {0.f, 0.f, 0.f, 0.f};
    float mc_acc[4][4];
#pragma unroll
    for (int p = 0; p < 4; p++)
#pragma unroll
        for (int rr = 0; rr < 4; rr++) mc_acc[p][rr] = -INFINITY;

#pragma unroll
    for (int jt_i = 0; jt_i < 3; jt_i++) {
        int j = (jq * 3 + jt_i) * 16 + lcol;
        float n2 = ws[WS_N2 + nbase + j];
#pragma unroll
        for (int rr = 0; rr < 4; rr++) {
            float den = n1[rr] * n2;
            float att = acc[0][jt_i][rr] / (den > EPSV ? den : EPSV);
            ws[WS_ATT + (size_t)(q1b + rr) * S2 + j] = att;
            satt_acc[rr] += att;
        }
#pragma unroll
        for (int p = 0; p < 4; p++) {
            float n2wv = fmaxf(ws[WS_N2W + (size_t)(nbase + j) * 4 + p], EPSV);
#pragma unroll
            for (int rr = 0; rr < 4; rr++) {
                float cosv = acc[p + 1][jt_i][rr] / (n1wc[rr][p] * n2wv);
                mc_acc[p][rr] = fmaxf(mc_acc[p][rr], cosv);
            }
        }
    }

    // reduce over the 16 column lanes (stays within each lane>>4 group)
#pragma unroll
    for (int m = 1; m < 16; m <<= 1) {
#pragma unroll
        for (int rr = 0; rr < 4; rr++) satt_acc[rr] += __shfl_xor(satt_acc[rr], m, 64);
#pragma unroll
        for (int p = 0; p < 4; p++)
#pragma unroll
            for (int rr = 0; rr < 4; rr++)
                mc_acc[p][rr] = fmaxf(mc_acc[p][rr], __shfl_xor(mc_acc[p][rr], m, 64));
    }
    if (lcol == 0) {
#pragma unroll
        for (int rr = 0; rr < 4; rr++) {
            ws[WS_SATT + jq * 4096 + q1b + rr] = satt_acc[rr];
#pragma unroll
            for (int p = 0; p < 4; p++)
                ws[WS_MC + (size_t)(jq * 4096 + q1b + rr) * 4 + p] = mc_acc[p][rr];
        }
    }
}

// Apply kernel: one wave per (b, i, d). Lane owns a float4 h-chunk.
__global__ __launch_bounds__(64) void apply_kernel(const float* __restrict__ q1,
                                                   const float* __restrict__ q2,
                                                   const float* __restrict__ W,
                                                   const float* __restrict__ ws,
                                                   float* __restrict__ out) {
    int bid = blockIdx.x;
    int b = bid >> 8;
    int i = (bid >> 1) & 127;
    int d = bid & 1;
    int lane = threadIdx.x;
    int h0 = lane * 4;

    int q1idx = d * (NB * S1) + b * S1 + i;
    const float* q1row = q1 + ((size_t)(b * S1 + i)) * FULLH + d * HH;
    float4 q1v = *reinterpret_cast<const float4*>(q1row + h0);
    const float* q2base = q2 + (size_t)b * S2 * FULLH + d * HH;
    const float* attrow = ws + WS_ATT + (size_t)q1idx * S2;

    float satt = ws[WS_SATT + 0 * 4096 + q1idx] + ws[WS_SATT + 1 * 4096 + q1idx] +
                 ws[WS_SATT + 2 * 4096 + q1idx] + ws[WS_SATT + 3 * 4096 + q1idx];

    size_t obase = ((size_t)(b * S1 + i)) * 32;
    if (lane < 4) {
        float m = -INFINITY;
#pragma unroll
        for (int jq = 0; jq < 4; jq++)
            m = fmaxf(m, ws[WS_MC + (size_t)(jq * 4096 + q1idx) * 4 + lane]);
        out[obase + 8 + 4 * d + lane] = m;
    }

    float4 macc = make_float4(0.f, 0.f, 0.f, 0.f);
    float4 mx = make_float4(-INFINITY, -INFINITY, -INFINITY, -INFINITY);
#pragma unroll 4
    for (int j = 0; j < S2; j++) {
        float att = attrow[j];
        float4 qv = *reinterpret_cast<const float4*>(q2base + (size_t)j * FULLH + h0);
        macc.x = fmaf(att, qv.x, macc.x);
        macc.y = fmaf(att, qv.y, macc.y);
        macc.z = fmaf(att, qv.z, macc.z);
        macc.w = fmaf(att, qv.w, macc.w);
        mx.x = fmaxf(mx.x, att * qv.x);
        mx.y = fmaxf(mx.y, att * qv.y);
        mx.z = fmaxf(mx.z, att * qv.z);
        mx.w = fmaxf(mx.w, att * qv.w);
    }
    float sden = satt > EPSV ? satt : EPSV;
    float4 mean;
    mean.x = macc.x / sden; mean.y = macc.y / sden;
    mean.z = macc.z / sden; mean.w = macc.w / sden;
    float4 rv = *reinterpret_cast<const float4*>(
        q2base + (d == 0 ? (size_t)(S2 - 1) * FULLH : (size_t)0) + h0);

    float s[36];
#pragma unroll
    for (int m = 0; m < 3; m++) {
        float4 xv = (m == 0) ? rv : (m == 1) ? mean : mx;
        int wb = (m == 0) ? d : (m == 1) ? 4 + d : 6 + d;
#pragma unroll
        for (int p = 0; p < 4; p++) {
            float4 wv = *reinterpret_cast<const float4*>(W + ((size_t)wb * PP + p) * HH + h0);
            float4 w2;
            w2.x = wv.x * wv.x; w2.y = wv.y * wv.y;
            w2.z = wv.z * wv.z; w2.w = wv.w * wv.w;
            float4 tq, u;
            tq.x = q1v.x * w2.x; tq.y = q1v.y * w2.y;
            tq.z = q1v.z * w2.z; tq.w = q1v.w * w2.w;
            u.x = xv.x * w2.x; u.y = xv.y * w2.y;
            u.z = xv.z * w2.z; u.w = xv.w * w2.w;
            int base = (m * 4 + p) * 3;
            s[base + 0] = tq.x * xv.x + tq.y * xv.y + tq.z * xv.z + tq.w * xv.w;
            s[base + 1] = tq.x * q1v.x + tq.y * q1v.y + tq.z * q1v.z + tq.w * q1v.w;
            s[base + 2] = u.x * xv.x + u.y * xv.y + u.z * xv.z + u.w * xv.w;
        }
    }
    wave_reduce_sum_n<36>(s);
    if (lane == 0) {
        const int obm[3] = {0, 16, 24};
#pragma unroll
        for (int m = 0; m < 3; m++) {
#pragma unroll
            for (int p = 0; p < 4; p++) {
                int base = (m * 4 + p) * 3;
                out[obase + obm[m] + 4 * d + p] =
                    s[base] / (fmaxf(sqrtf(s[base + 1]), EPSV) *
                               fmaxf(sqrtf(s[base + 2]), EPSV));
            }
        }
    }
}

extern "C" void kernel_launch(void* const* d_in, const int* in_sizes, int n_in,
                              void* d_out, int out_size, void* d_ws, size_t ws_size,
                              hipStream_t stream) {
    const float* q1 = (const float*)d_in[0];
    const float* q2 = (const float*)d_in[1];
    const float* W = (const float*)d_in[2];
    float* out = (float*)d_out;
    float* ws = (float*)d_ws;

    int nrows = 2 * NB * S2 + 2 * NB * S1;             // 10240 waves
    int nblocks_norm = (nrows * 64 + 255) / 256;       // 2560
    norms_kernel<<<dim3(nblocks_norm), dim3(256), 0, stream>>>(q1, q2, W, ws);

    s_mfma_kernel<<<dim3(2 * NB * 8 * 4), dim3(64), 0, stream>>>(q1, W, ws);

    apply_kernel<<<dim3(NB * S1 * 2), dim3(64), 0, stream>>>(q1, q2, W, ws, out);
}